// Round 2
// baseline (225.652 us; speedup 1.0000x reference)
//
#include <hip/hip_runtime.h>
#include <hip/hip_bf16.h>

typedef __attribute__((ext_vector_type(8))) short bf16x8;
typedef __attribute__((ext_vector_type(8))) unsigned short u16x8;
typedef __attribute__((ext_vector_type(4))) float f32x4;

// ---------------- workspace layout (bytes) ----------------
// 0        : rnorm   f32[8192]
// 32K      : flags   i32[8192]
// 64K      : idx_sel i32[8192]
// 96K      : labels_sel i32[8192]
// 128K     : meta    i32[2]  (S, Spad)
// 256K     : fsel    bf16[8192*1024]   (16 MB)
// 256K+16M : sim     f32[Spad*Spad]    (~32 MB for S~2731)

#define OFF_RNORM   0
#define OFF_FLAGS   (32*1024)
#define OFF_IDXSEL  (64*1024)
#define OFF_LBLSEL  (96*1024)
#define OFF_META    (128*1024)
#define OFF_FSEL    (256*1024)

__device__ inline unsigned short f2bf(float f){
    union { __hip_bfloat16 h; unsigned short u; } cv;
    cv.h = __float2bfloat16(f);
    return cv.u;
}

// -------- kernel 1: row norms + selection flags --------
__global__ __launch_bounds__(256) void prep_kernel(
    const float* __restrict__ feats, const float* __restrict__ score,
    const int* __restrict__ type_idx, float* __restrict__ rnorm,
    int* __restrict__ flags, int D)
{
    int r = blockIdx.x, tid = threadIdx.x;
    const float4* fr = (const float4*)(feats + (size_t)r * D);
    float ssq = 0.f;
    int nv = D >> 2;
    for (int i = tid; i < nv; i += 256) {
        float4 v = fr[i];
        ssq += v.x*v.x + v.y*v.y + v.z*v.z + v.w*v.w;
    }
    for (int o = 32; o; o >>= 1) ssq += __shfl_down(ssq, o);
    __shared__ float sm[4];
    if ((tid & 63) == 0) sm[tid >> 6] = ssq;
    __syncthreads();
    if (tid == 0) {
        float t = sm[0] + sm[1] + sm[2] + sm[3];
        rnorm[r] = 1.0f / fmaxf(sqrtf(t), 1e-12f);
        float s0 = score[3*r], s1 = score[3*r+1], s2 = score[3*r+2];
        int am = 0; float b = s0;
        if (s1 > b) { b = s1; am = 1; }
        if (s2 > b) { am = 2; }
        flags[r] = (am == type_idx[0]) ? 1 : 0;
    }
}

// -------- kernel 2: single-block compaction (ballot scan) --------
__global__ __launch_bounds__(256) void compact_kernel(
    const int* __restrict__ flags, const void* __restrict__ labels_raw,
    int* __restrict__ idx_sel, int* __restrict__ labels_sel,
    int* __restrict__ meta, int B)
{
    __shared__ int swt[4];
    __shared__ int s_total;
    __shared__ int s_is64;
    int tid = threadIdx.x, lane = tid & 63, wid = tid >> 6;
    if (tid == 0) {
        s_total = 0;
        // labels may be int64 (reference dtype) or int32 (harness doc).
        // int64 values in [0,128): every high word is 0. For int32 data the
        // odd-index values are uniform in [0,128) -> P(all 128 zero) ~ 0.
        const int* li = (const int*)labels_raw;
        int nz = 0;
        for (int j = 0; j < 128; j++) nz |= li[2*j + 1];
        s_is64 = (nz == 0) ? 1 : 0;
    }
    __syncthreads();
    int is64 = s_is64;
    const int* l32 = (const int*)labels_raw;
    const long long* l64 = (const long long*)labels_raw;
    for (int base = 0; base < B; base += 256) {
        int i = base + tid;
        int f = flags[i];
        unsigned long long b = __ballot(f != 0);
        int incl = __popcll(b & ((2ULL << lane) - 1ULL));
        if (lane == 63) swt[wid] = incl;
        __syncthreads();
        int wprefix = 0;
        for (int w = 0; w < wid; w++) wprefix += swt[w];
        int total = s_total;
        if (f) {
            int pos = total + wprefix + incl - 1;
            idx_sel[pos] = i;
            labels_sel[pos] = is64 ? (int)l64[i] : l32[i];
        }
        __syncthreads();
        if (tid == 0) s_total = total + swt[0] + swt[1] + swt[2] + swt[3];
        __syncthreads();
    }
    if (tid == 0) {
        int S = s_total;
        meta[0] = S;
        meta[1] = ((S + 127) / 128) * 128;   // Spad
    }
}

// -------- kernel 3: gather selected rows, normalize, cast bf16 --------
__global__ __launch_bounds__(256) void gather_kernel(
    const float* __restrict__ feats, const float* __restrict__ rnorm,
    const int* __restrict__ idx_sel, const int* __restrict__ meta,
    unsigned short* __restrict__ fsel, int D)
{
    int s = blockIdx.x;
    int S = meta[0], Spad = meta[1];
    if (s >= Spad) return;
    int tid = threadIdx.x;
    int nv = D >> 2;
    ushort4* dst = (ushort4*)(fsel + (size_t)s * D);
    if (s < S) {
        int r = idx_sel[s];
        float sc = rnorm[r];
        const float4* src = (const float4*)(feats + (size_t)r * D);
        for (int i = tid; i < nv; i += 256) {
            float4 v = src[i];
            ushort4 o;
            o.x = f2bf(v.x * sc); o.y = f2bf(v.y * sc);
            o.z = f2bf(v.z * sc); o.w = f2bf(v.w * sc);
            dst[i] = o;
        }
    } else {
        ushort4 z = {0,0,0,0};
        for (int i = tid; i < nv; i += 256) dst[i] = z;
    }
}

// -------- kernel 4: sim = fsel * fsel^T  (bf16 MFMA, 128x128 tile) --------
// LDS layout kb-major: chunk c in [0,512): kb=c>>7, r=c&127 holds
// row (tile+r), k in [k0+kb*8, +8). Fragment ds_read_b128 is conflict-free.
__global__ __launch_bounds__(256) void simgemm_kernel(
    const unsigned short* __restrict__ fsel, const int* __restrict__ meta,
    float* __restrict__ sim, int D)
{
    int Spad = meta[1];
    int bm = blockIdx.x * 128, bn = blockIdx.y * 128;
    if (bm >= Spad || bn >= Spad) return;

    __shared__ unsigned short lA[512 * 8];   // 8 KB
    __shared__ unsigned short lB[512 * 8];   // 8 KB

    int tid = threadIdx.x;
    int lane = tid & 63;
    int wave = tid >> 6;
    int wr = (wave >> 1) * 64;   // wave row offset in tile
    int wc = (wave & 1) * 64;    // wave col offset in tile
    int laneRow = lane & 15;
    int laneK = lane >> 4;       // kb 0..3

    f32x4 acc[4][4];
#pragma unroll
    for (int m = 0; m < 4; m++)
#pragma unroll
        for (int n = 0; n < 4; n++)
            acc[m][n] = (f32x4){0.f, 0.f, 0.f, 0.f};

    for (int k0 = 0; k0 < D; k0 += 32) {
        __syncthreads();   // protect LDS from previous iteration's readers
#pragma unroll
        for (int p = 0; p < 2; p++) {
            int c = tid + p * 256;
            int kb = c >> 7, r = c & 127;
            const unsigned short* gA = fsel + (size_t)(bm + r) * D + k0 + kb * 8;
            const unsigned short* gB = fsel + (size_t)(bn + r) * D + k0 + kb * 8;
            u16x8 va = *(const u16x8*)gA;
            u16x8 vb = *(const u16x8*)gB;
            *(u16x8*)&lA[(size_t)c * 8] = va;
            *(u16x8*)&lB[(size_t)c * 8] = vb;
        }
        __syncthreads();

        bf16x8 af[4], bfrag[4];
#pragma unroll
        for (int m = 0; m < 4; m++) {
            int row = wr + m * 16 + laneRow;
            af[m] = *(const bf16x8*)&lA[(laneK * 128 + row) * 8];
            int col = wc + m * 16 + laneRow;
            bfrag[m] = *(const bf16x8*)&lB[(laneK * 128 + col) * 8];
        }
#pragma unroll
        for (int m = 0; m < 4; m++)
#pragma unroll
            for (int n = 0; n < 4; n++)
                acc[m][n] = __builtin_amdgcn_mfma_f32_16x16x32_bf16(
                    af[m], bfrag[n], acc[m][n], 0, 0, 0);
    }

    // C/D layout: col = lane&15, row = (lane>>4)*4 + q   [m89-verified]
#pragma unroll
    for (int m = 0; m < 4; m++) {
        int row0 = bm + wr + m * 16 + (lane >> 4) * 4;
#pragma unroll
        for (int n = 0; n < 4; n++) {
            int col = bn + wc + n * 16 + laneRow;
#pragma unroll
            for (int q = 0; q < 4; q++)
                sim[(size_t)(row0 + q) * Spad + col] = acc[m][n][q];
        }
    }
}

// -------- kernel 5: per-selected-row loss, atomicAdd scalar --------
__global__ __launch_bounds__(256) void loss_kernel(
    const float* __restrict__ sim, const int* __restrict__ labels_sel,
    const int* __restrict__ meta, float* __restrict__ out, float invB)
{
    int s = blockIdx.x;
    int S = meta[0];
    if (s >= S) return;
    int Spad = meta[1];
    int tid = threadIdx.x;
    const float* row = sim + (size_t)s * Spad;
    const float ONE_ME = 1.0f - 1e-5f;

    __shared__ int slbl[8192];
    for (int j = tid; j < S; j += 256) slbl[j] = labels_sel[j];
    __syncthreads();
    int lbl = slbl[s];

    // pass 1: count, min over positives (<1-eps), max over negatives
    int cnt = 0;
    float minp = INFINITY, maxn = -INFINITY;
    for (int j = tid; j < S; j += 256) {
        float sv = (j == s) ? 1.0f : row[j];
        if (slbl[j] == lbl) {
            cnt++;
            if (sv < ONE_ME) minp = fminf(minp, sv);
        } else {
            maxn = fmaxf(maxn, sv);
        }
    }
    for (int o = 32; o; o >>= 1) {
        cnt += __shfl_down(cnt, o);
        minp = fminf(minp, __shfl_down(minp, o));
        maxn = fmaxf(maxn, __shfl_down(maxn, o));
    }
    __shared__ float sred[8];
    __shared__ int sredi[4];
    int wid = tid >> 6;
    if ((tid & 63) == 0) { sredi[wid] = cnt; sred[wid] = minp; sred[4 + wid] = maxn; }
    __syncthreads();
    if (tid == 0) {
        int c = 0; float mp = INFINITY, mn = -INFINITY;
        for (int w = 0; w < 4; w++) {
            c += sredi[w];
            mp = fminf(mp, sred[w]);
            mn = fmaxf(mn, sred[4 + w]);
        }
        sredi[0] = c; sred[0] = mp; sred[4] = mn;
    }
    __syncthreads();
    cnt = sredi[0]; minp = sred[0]; maxn = sred[4];
    __syncthreads();

    if (!(cnt > 1 && minp < 3e38f && maxn > -3e38f)) return; // invalid row

    // pass 2: hard-pair exp sums
    float psum = 0.f, nsum = 0.f;
    for (int j = tid; j < S; j += 256) {
        float sv = (j == s) ? 1.0f : row[j];
        if (slbl[j] == lbl) {
            if (sv < ONE_ME && sv - 0.1f < maxn) psum += expf(-2.0f * (sv - 0.5f));
        } else {
            if (sv + 0.1f > minp) nsum += expf(40.0f * (sv - 0.5f));
        }
    }
    for (int o = 32; o; o >>= 1) {
        psum += __shfl_down(psum, o);
        nsum += __shfl_down(nsum, o);
    }
    if ((tid & 63) == 0) { sred[wid] = psum; sred[4 + wid] = nsum; }
    __syncthreads();
    if (tid == 0) {
        float ps = sred[0] + sred[1] + sred[2] + sred[3];
        float ns = sred[4] + sred[5] + sred[6] + sred[7];
        // any(pos_sel) <=> ps>0, any(neg_sel) <=> ns>0 (exp never underflows to 0 here)
        if (ps > 0.f && ns > 0.f) {
            float rl = log1pf(ps) * 0.5f + log1pf(ns) * 0.025f;
            atomicAdd(out, rl * invB);
        }
    }
}

extern "C" void kernel_launch(void* const* d_in, const int* in_sizes, int n_in,
                              void* d_out, int out_size, void* d_ws, size_t ws_size,
                              hipStream_t stream)
{
    const float* feats   = (const float*)d_in[0];
    const void*  labels  = d_in[1];
    const float* score   = (const float*)d_in[2];
    const int*   type_idx= (const int*)d_in[3];

    int B = in_sizes[1];           // 8192
    int D = in_sizes[0] / B;       // 1024

    char* ws = (char*)d_ws;
    float* rnorm      = (float*)(ws + OFF_RNORM);
    int*   flags      = (int*)  (ws + OFF_FLAGS);
    int*   idx_sel    = (int*)  (ws + OFF_IDXSEL);
    int*   labels_sel = (int*)  (ws + OFF_LBLSEL);
    int*   meta       = (int*)  (ws + OFF_META);
    unsigned short* fsel = (unsigned short*)(ws + OFF_FSEL);
    float* sim        = (float*)(ws + OFF_FSEL + (size_t)B * D * 2);
    float* out        = (float*)d_out;

    (void)hipMemsetAsync(d_out, 0, (size_t)out_size * sizeof(float), stream);

    prep_kernel<<<B, 256, 0, stream>>>(feats, score, type_idx, rnorm, flags, D);
    compact_kernel<<<1, 256, 0, stream>>>(flags, labels, idx_sel, labels_sel, meta, B);
    gather_kernel<<<B, 256, 0, stream>>>(feats, rnorm, idx_sel, meta, fsel, D);
    dim3 g((B + 127) / 128, (B + 127) / 128);
    simgemm_kernel<<<g, 256, 0, stream>>>(fsel, meta, sim, D);
    loss_kernel<<<B, 256, 0, stream>>>(sim, labels_sel, meta, out, 1.0f / (float)B);
}